// Round 2
// baseline (1573.152 us; speedup 1.0000x reference)
//
#include <hip/hip_runtime.h>
#include <math.h>
#include <stdint.h>

#define B_   4
#define S_   2048
#define DM_  1024
#define H_   16
#define DK_  64

typedef __bf16 bhalf;
typedef __bf16 bhalf8 __attribute__((ext_vector_type(8)));
typedef float  f32x4  __attribute__((ext_vector_type(4)));

typedef const __attribute__((address_space(1))) void g_void;
typedef __attribute__((address_space(3))) void l_void;

// async global->LDS, 16B per lane. LDS dest must be wave-uniform base + lane*16.
__device__ __forceinline__ void gld16(const void* g, void* l) {
  __builtin_amdgcn_global_load_lds((g_void*)g, (l_void*)l, 16, 0, 0);
}

// ---------------- fp32 -> bf16 convert, 8 elems/thread ----------------
__global__ __launch_bounds__(256) void cvt_kernel(const float* __restrict__ src,
                                                  bhalf* __restrict__ dst, int n) {
  int i = (blockIdx.x * 256 + threadIdx.x) * 8;
  if (i >= n) return;
  float4 a = *(const float4*)(src + i);
  float4 b = *(const float4*)(src + i + 4);
  bhalf8 o;
  o[0] = (bhalf)a.x; o[1] = (bhalf)a.y; o[2] = (bhalf)a.z; o[3] = (bhalf)a.w;
  o[4] = (bhalf)b.x; o[5] = (bhalf)b.y; o[6] = (bhalf)b.z; o[7] = (bhalf)b.w;
  *(bhalf8*)(dst + i) = o;
}

// ---------------- mask int32 -> bit-packed u64 words ----------------
__global__ __launch_bounds__(256) void maskpack_kernel(const int* __restrict__ mask,
                                                       unsigned long long* __restrict__ out) {
  int i = blockIdx.x * 256 + threadIdx.x;   // over B*S*S
  unsigned long long bits = __ballot(mask[i] != 0);
  if ((threadIdx.x & 63) == 0) out[i >> 6] = bits;
}

// ---------------- bf16 GEMM  C[M=8192, N=1024] = A * B^T  (K=1024) ----------------
template <int MODE>
__global__ __launch_bounds__(256) void gemm_bt(const bhalf* __restrict__ A,
                                               const bhalf* __restrict__ Bm,
                                               bhalf* __restrict__ d16,
                                               float* __restrict__ d32,
                                               const float* __restrict__ bias,
                                               float scale) {
  constexpr int K = 1024;
  __shared__ __align__(16) bhalf As[128 * 64];
  __shared__ __align__(16) bhalf Bs[128 * 64];
  const int tid = threadIdx.x;
  const int lane = tid & 63;
  const int w = tid >> 6;
  const int wm = w & 1, wn = w >> 1;
  const int bm = blockIdx.y, bn = blockIdx.x;
  const bhalf* Ab = A + (long)bm * 128 * K;
  const bhalf* Bb = Bm + (long)bn * 128 * K;
  const int l15 = lane & 15, l4 = lane >> 4;
  f32x4 acc[4][4] = {};
  for (int kt = 0; kt < K / 64; ++kt) {
#pragma unroll
    for (int j = 0; j < 4; ++j) {
      int c = j * 256 + tid;                 // 1024 chunks of 16B per tile
      int r = c >> 3, ko = (c & 7) * 8;
      gld16(Ab + (long)r * K + kt * 64 + ko, &As[c * 8]);
      gld16(Bb + (long)r * K + kt * 64 + ko, &Bs[c * 8]);
    }
    __syncthreads();
#pragma unroll
    for (int t = 0; t < 2; ++t) {
      bhalf8 af[4], bfr[4];
#pragma unroll
      for (int i = 0; i < 4; ++i)
        af[i] = *(const bhalf8*)&As[(wm * 64 + i * 16 + l15) * 64 + t * 32 + l4 * 8];
#pragma unroll
      for (int j = 0; j < 4; ++j)
        bfr[j] = *(const bhalf8*)&Bs[(wn * 64 + j * 16 + l15) * 64 + t * 32 + l4 * 8];
#pragma unroll
      for (int i = 0; i < 4; ++i)
#pragma unroll
        for (int j = 0; j < 4; ++j)
          acc[i][j] = __builtin_amdgcn_mfma_f32_16x16x32_bf16(af[i], bfr[j], acc[i][j], 0, 0, 0);
    }
    __syncthreads();
  }
#pragma unroll
  for (int i = 0; i < 4; ++i) {
#pragma unroll
    for (int j = 0; j < 4; ++j) {
#pragma unroll
      for (int r = 0; r < 4; ++r) {
        int gm = bm * 128 + wm * 64 + i * 16 + l4 * 4 + r;
        int gn = bn * 128 + wn * 64 + j * 16 + l15;
        float v = acc[i][j][r];
        if (MODE == 0) {
          int b = gm >> 11, s = gm & 2047, h = gn >> 6, d = gn & 63;
          d16[((long)(b * H_ + h) * S_ + s) * DK_ + d] = (bhalf)(v * scale);
        } else if (MODE == 1) {
          int b = gm >> 11, s = gm & 2047, h = gn >> 6, d = gn & 63;
          d16[((long)(b * H_ + h) * DK_ + d) * S_ + s] = (bhalf)v;
        } else {
          d32[(long)gm * 1024 + gn] = v + bias[gn];
        }
      }
    }
  }
}

// ---------------- staging helpers for attn (pre-swizzled global source, linear LDS dest) ----
// K tile: 128 rows x 64 bf16 (128 B rows), swizzle byte ^= (row&7)<<4
__device__ __forceinline__ void stage_k(const char* Kg, bhalf* dst, int tid) {
#pragma unroll
  for (int j = 0; j < 4; ++j) {
    int c = j * 256 + tid, r = c >> 3, ko = (c & 7) * 16;
    gld16(Kg + r * 128 + (ko ^ ((r & 7) << 4)), (char*)dst + c * 16);
  }
}
// V tile: 64 rows (d) x 128 bf16 (256 B rows) gathered from Vt[d][S], swizzle byte ^= (d&15)<<4
__device__ __forceinline__ void stage_v(const char* Vg, bhalf* dst, int tid) {
#pragma unroll
  for (int j = 0; j < 4; ++j) {
    int c = j * 256 + tid, d = c >> 4, so = (c & 15) * 16;
    gld16(Vg + (long)d * (S_ * 2) + (so ^ ((d & 15) << 4)), (char*)dst + c * 16);
  }
}

// ---------------- fused attention: scores+mask+softmax+P-write+PV ----------------
// grid: B*H*16 workgroups; each handles (b,h, 128-row q tile), two passes over K.
// Schedule: K double-buffered + counted s_waitcnt vmcnt(N) + raw s_barrier (never drain
// vmcnt to 0 in steady state). Qh is pre-scaled by (1/sqrt(dk))*log2(e); pass-2 folds
// -log2(rowsum) into the MFMA C-init so P = exp2(score_acc) directly.
__global__ __launch_bounds__(256, 2) void attn_kernel(const bhalf* __restrict__ Qh,
                                                      const bhalf* __restrict__ Kh,
                                                      const bhalf* __restrict__ Vt,
                                                      const unsigned long long* __restrict__ mb,
                                                      bhalf* __restrict__ ctx,
                                                      float* __restrict__ att) {
  // exactly 80 KB LDS -> 2 blocks/CU
  __shared__ __align__(16) bhalf Kbuf[2][128 * 64];  // 32 KB, swizzled ^(r&7)<<4
  __shared__ __align__(16) bhalf Vs[64 * 128];       // 16 KB, swizzled ^(d&15)<<4; aliases rsum in pass 1
  __shared__ __align__(16) bhalf Ps[128 * 128];      // 32 KB, swizzled ^(q&15)<<4; Q staging at prologue
  float* rsum = (float*)Vs;

  const int tid = threadIdx.x, lane = tid & 63, w = tid >> 6;
  const int wm = w & 1, wn = w >> 1;
  const int l15 = lane & 15, l4 = lane >> 4;
  const int bid = blockIdx.x;
  const int qt = bid & 15;
  const int bh = bid >> 4;        // b*16 + h
  const int b = bh >> 4;
  const long qkBase = (long)bh * S_ * DK_;
  const bhalf* Kbase = Kh + qkBase;
  const char*  Vbase = (const char*)(Vt + qkBase);
  const int lrow0 = wm * 64 + l4 * 4;
  const long mrowbase = ((long)b * S_ + qt * 128 + lrow0) * 32 + wn;

  if (tid < 128) rsum[tid] = 0.f;

  // ---- prologue: stage Q (linear) into Ps, K(0) into Kbuf[0] ----
  {
    const bhalf* Qg = Qh + qkBase + (long)qt * 128 * DK_;
#pragma unroll
    for (int j = 0; j < 4; ++j) { int c = j * 256 + tid; gld16(Qg + c * 8, (char*)Ps + c * 16); }
  }
  stage_k((const char*)Kbase, Kbuf[0], tid);
  asm volatile("s_waitcnt vmcnt(4) lgkmcnt(0)" ::: "memory");  // Q landed (K0 stays in flight)
  __builtin_amdgcn_s_barrier();

  // hoist Q fragments into registers (loop-invariant for both passes)
  bhalf8 qf[4][2];
#pragma unroll
  for (int i = 0; i < 4; ++i)
#pragma unroll
    for (int t = 0; t < 2; ++t)
      qf[i][t] = *(const bhalf8*)((const char*)Ps + (wm * 64 + i * 16 + l15) * 128 + t * 64 + l4 * 16);

  unsigned long long mw[4][4];
#pragma unroll
  for (int i = 0; i < 4; ++i)
#pragma unroll
    for (int r = 0; r < 4; ++r) mw[i][r] = mb[mrowbase + (i * 16 + r) * 32];

  // -------- pass 1: row sums of exp2(s) --------
  float psum[4][4] = {};
#pragma unroll 1
  for (int kt = 0; kt < 16; ++kt) {
    if (kt < 15) {
      stage_k((const char*)(Kbase + (kt + 1) * 128 * DK_), Kbuf[(kt + 1) & 1], tid);
      asm volatile("s_waitcnt vmcnt(4)" ::: "memory");   // K(kt)+M(kt) landed, K(kt+1) in flight
    } else {
      asm volatile("s_waitcnt vmcnt(0)" ::: "memory");
    }
    __builtin_amdgcn_s_barrier();
    const bhalf* Kc = Kbuf[kt & 1];
#pragma unroll
    for (int i = 0; i < 4; ++i) {
      unsigned int mlo[4], mhi[4];
#pragma unroll
      for (int r = 0; r < 4; ++r) {
        unsigned long long sh = mw[i][r] >> l15;
        mlo[r] = (unsigned int)sh; mhi[r] = (unsigned int)(sh >> 32);
      }
#pragma unroll
      for (int jn = 0; jn < 4; ++jn) {
        const int kr = wn * 64 + jn * 16 + l15;
        bhalf8 bk0 = *(const bhalf8*)((const char*)Kc + ((kr * 128 + l4 * 16) ^ ((kr & 7) << 4)));
        bhalf8 bk1 = *(const bhalf8*)((const char*)Kc + ((kr * 128 + 64 + l4 * 16) ^ ((kr & 7) << 4)));
        f32x4 sacc = {};
        sacc = __builtin_amdgcn_mfma_f32_16x16x32_bf16(qf[i][0], bk0, sacc, 0, 0, 0);
        sacc = __builtin_amdgcn_mfma_f32_16x16x32_bf16(qf[i][1], bk1, sacc, 0, 0, 0);
#pragma unroll
        for (int r = 0; r < 4; ++r) {
          unsigned int on = (jn < 2 ? mlo[r] : mhi[r]) & (1u << ((jn & 1) * 16));
          psum[i][r] += on ? __builtin_amdgcn_exp2f(sacc[r]) : 0.f;
        }
      }
    }
    if (kt < 15) {   // prefetch next mask words under this tile's compute
#pragma unroll
      for (int i = 0; i < 4; ++i)
#pragma unroll
        for (int r = 0; r < 4; ++r) mw[i][r] = mb[mrowbase + (i * 16 + r) * 32 + (kt + 1) * 2];
    }
    __builtin_amdgcn_s_barrier();
  }

  // reduce across the 16 lanes holding one row's columns -> rsum, then l2r = -log2(rsum)
#pragma unroll
  for (int i = 0; i < 4; ++i)
#pragma unroll
    for (int r = 0; r < 4; ++r) {
      float v = psum[i][r];
      v += __shfl_xor(v, 1); v += __shfl_xor(v, 2);
      v += __shfl_xor(v, 4); v += __shfl_xor(v, 8);
      if (l15 == 0) atomicAdd(&rsum[lrow0 + i * 16 + r], v);
    }
  __syncthreads();
  if (tid < 128) rsum[tid] = -__log2f(rsum[tid]);
  __syncthreads();
  float l2r[4][4];
#pragma unroll
  for (int i = 0; i < 4; ++i)
#pragma unroll
    for (int r = 0; r < 4; ++r) l2r[i][r] = rsum[lrow0 + i * 16 + r];
  __syncthreads();   // rsum reads done before V(0) staging overwrites Vs

  // -------- pass 2 prologue: K(0), M(0), V(0) in flight --------
  stage_k((const char*)Kbase, Kbuf[0], tid);
#pragma unroll
  for (int i = 0; i < 4; ++i)
#pragma unroll
    for (int r = 0; r < 4; ++r) mw[i][r] = mb[mrowbase + (i * 16 + r) * 32];
  stage_v(Vbase, Vs, tid);

  f32x4 oacc[2][4] = {};
  const int prow = w * 32;   // PV: wave w handles q rows [prow, prow+32)
#pragma unroll 1
  for (int kt = 0; kt < 16; ++kt) {
    const int cur = kt & 1;
    if (kt < 15) {
      stage_k((const char*)(Kbase + (kt + 1) * 128 * DK_), Kbuf[cur ^ 1], tid);
      asm volatile("s_waitcnt vmcnt(8)" ::: "memory");   // K(kt)+M(kt) landed; keep V(kt)+K(kt+1)
    } else {
      asm volatile("s_waitcnt vmcnt(4)" ::: "memory");   // keep V(15)
    }
    __builtin_amdgcn_s_barrier();
    const bhalf* Kc = Kbuf[cur];
    // QK^T + mask + exp2 (with -log2(rowsum) as C-init) + immediate P write
#pragma unroll
    for (int i = 0; i < 4; ++i) {
      f32x4 cin;
      unsigned int mlo[4], mhi[4];
#pragma unroll
      for (int r = 0; r < 4; ++r) {
        cin[r] = l2r[i][r];
        unsigned long long sh = mw[i][r] >> l15;
        mlo[r] = (unsigned int)sh; mhi[r] = (unsigned int)(sh >> 32);
      }
#pragma unroll
      for (int jn = 0; jn < 4; ++jn) {
        const int kr = wn * 64 + jn * 16 + l15;
        bhalf8 bk0 = *(const bhalf8*)((const char*)Kc + ((kr * 128 + l4 * 16) ^ ((kr & 7) << 4)));
        bhalf8 bk1 = *(const bhalf8*)((const char*)Kc + ((kr * 128 + 64 + l4 * 16) ^ ((kr & 7) << 4)));
        f32x4 sacc = cin;
        sacc = __builtin_amdgcn_mfma_f32_16x16x32_bf16(qf[i][0], bk0, sacc, 0, 0, 0);
        sacc = __builtin_amdgcn_mfma_f32_16x16x32_bf16(qf[i][1], bk1, sacc, 0, 0, 0);
        const int pc2 = (wn * 64 + jn * 16 + l15) * 2;
#pragma unroll
        for (int r = 0; r < 4; ++r) {
          unsigned int on = (jn < 2 ? mlo[r] : mhi[r]) & (1u << ((jn & 1) * 16));
          float p = on ? __builtin_amdgcn_exp2f(sacc[r]) : 0.f;
          const int pr = lrow0 + i * 16 + r;
          *(bhalf*)((char*)Ps + pr * 256 + (pc2 ^ ((pr & 15) << 4))) = (bhalf)p;
        }
      }
    }
    // P writes visible + V(kt) landed (K(kt+1) stays in flight)
    if (kt < 15) asm volatile("s_waitcnt vmcnt(4) lgkmcnt(0)" ::: "memory");
    else         asm volatile("s_waitcnt vmcnt(0) lgkmcnt(0)" ::: "memory");
    __builtin_amdgcn_s_barrier();
    // coalesced normalized-attention write (fp32, nontemporal)
    {
      float* dst = att + ((long)bh * S_ + qt * 128) * S_ + kt * 128;
#pragma unroll
      for (int rep = 0; rep < 8; ++rep) {
        int idx = rep * 256 + tid;      // 2048 groups of 8 bf16
        int row = idx >> 4, slot = idx & 15;
        bhalf8 p8 = *(const bhalf8*)((const char*)Ps + row * 256 + ((slot * 16) ^ ((row & 15) << 4)));
        f32x4 o0, o1;
        o0[0] = (float)p8[0]; o0[1] = (float)p8[1]; o0[2] = (float)p8[2]; o0[3] = (float)p8[3];
        o1[0] = (float)p8[4]; o1[1] = (float)p8[5]; o1[2] = (float)p8[6]; o1[3] = (float)p8[7];
        float* dp = dst + (long)row * S_ + slot * 8;
        __builtin_nontemporal_store(o0, (f32x4*)dp);
        __builtin_nontemporal_store(o1, (f32x4*)(dp + 4));
      }
    }
    // PV: oacc += P(128x128) * V(128x64)
    __builtin_amdgcn_s_setprio(1);
#pragma unroll
    for (int t = 0; t < 4; ++t) {
      bhalf8 ap[2], bv[4];
#pragma unroll
      for (int mi = 0; mi < 2; ++mi) {
        const int pr = prow + mi * 16 + l15;
        ap[mi] = *(const bhalf8*)((const char*)Ps + pr * 256 + ((t * 64 + l4 * 16) ^ ((pr & 15) << 4)));
      }
#pragma unroll
      for (int nj = 0; nj < 4; ++nj) {
        const int vr = nj * 16 + l15;
        bv[nj] = *(const bhalf8*)((const char*)Vs + vr * 256 + ((t * 64 + l4 * 16) ^ ((vr & 15) << 4)));
      }
#pragma unroll
      for (int mi = 0; mi < 2; ++mi)
#pragma unroll
        for (int nj = 0; nj < 4; ++nj)
          oacc[mi][nj] = __builtin_amdgcn_mfma_f32_16x16x32_bf16(ap[mi], bv[nj], oacc[mi][nj], 0, 0, 0);
    }
    __builtin_amdgcn_s_setprio(0);
    __builtin_amdgcn_s_barrier();   // all Ps/Vs reads done before restage
    if (kt < 15) {
#pragma unroll
      for (int i = 0; i < 4; ++i)   // M(kt+1) before V(kt+1): drain order matters
#pragma unroll
        for (int r = 0; r < 4; ++r) mw[i][r] = mb[mrowbase + (i * 16 + r) * 32 + (kt + 1) * 2];
      stage_v(Vbase + (kt + 1) * 256, Vs, tid);
    }
  }
  // write context (bf16) into [B*S, DM] assembly buffer
#pragma unroll
  for (int mi = 0; mi < 2; ++mi)
#pragma unroll
    for (int nj = 0; nj < 4; ++nj)
#pragma unroll
      for (int r = 0; r < 4; ++r) {
        int lq = prow + mi * 16 + l4 * 4 + r;
        int d = nj * 16 + l15;
        int gq = qt * 128 + lq;
        ctx[((long)(b * S_ + gq)) * DM_ + (bh & 15) * DK_ + d] = (bhalf)oacc[mi][nj][r];
      }
}

extern "C" void kernel_launch(void* const* d_in, const int* in_sizes, int n_in,
                              void* d_out, int out_size, void* d_ws, size_t ws_size,
                              hipStream_t stream) {
  const float* q  = (const float*)d_in[0];
  const float* k  = (const float*)d_in[1];
  const float* v  = (const float*)d_in[2];
  const int*   mask = (const int*)d_in[3];
  const float* Wq = (const float*)d_in[4];
  const float* Wk = (const float*)d_in[5];
  const float* Wv = (const float*)d_in[6];
  const float* Wo = (const float*)d_in[7];
  const float* bo = (const float*)d_in[8];
  float* out = (float*)d_out;
  float* att = out + (size_t)B_ * S_ * DM_;

  char* ws = (char*)d_ws;
  bhalf* qb  = (bhalf*)(ws);
  bhalf* kb  = (bhalf*)(ws + (16ull << 20));
  bhalf* vb  = (bhalf*)(ws + (32ull << 20));
  bhalf* Wqb = (bhalf*)(ws + (48ull << 20));
  bhalf* Wkb = (bhalf*)(ws + (50ull << 20));
  bhalf* Wvb = (bhalf*)(ws + (52ull << 20));
  bhalf* Wob = (bhalf*)(ws + (54ull << 20));
  bhalf* Qh  = (bhalf*)(ws + (56ull << 20));
  bhalf* Kh  = (bhalf*)(ws + (72ull << 20));
  bhalf* Vt  = (bhalf*)(ws + (88ull << 20));
  bhalf* ctx = (bhalf*)(ws + (104ull << 20));
  unsigned long long* mb = (unsigned long long*)(ws + (120ull << 20));

  const int NQKV = B_ * S_ * DM_;    // 8388608
  const int NW = DM_ * DM_;          // 1048576
  cvt_kernel<<<NQKV / 2048, 256, 0, stream>>>(q, qb, NQKV);
  cvt_kernel<<<NQKV / 2048, 256, 0, stream>>>(k, kb, NQKV);
  cvt_kernel<<<NQKV / 2048, 256, 0, stream>>>(v, vb, NQKV);
  cvt_kernel<<<NW / 2048, 256, 0, stream>>>(Wq, Wqb, NW);
  cvt_kernel<<<NW / 2048, 256, 0, stream>>>(Wk, Wkb, NW);
  cvt_kernel<<<NW / 2048, 256, 0, stream>>>(Wv, Wvb, NW);
  cvt_kernel<<<NW / 2048, 256, 0, stream>>>(Wo, Wob, NW);
  maskpack_kernel<<<(B_ * S_ * S_) / 256, 256, 0, stream>>>(mask, mb);

  dim3 gg(DM_ / 128, (B_ * S_) / 128);   // (8, 64)
  // Qh scale = (1/sqrt(dk)) * log2(e) so scores are in the exp2 domain
  gemm_bt<0><<<gg, 256, 0, stream>>>(qb, Wqb, Qh, nullptr, nullptr, 0.18033688011112042f);
  gemm_bt<0><<<gg, 256, 0, stream>>>(kb, Wkb, Kh, nullptr, nullptr, 1.0f);
  gemm_bt<1><<<gg, 256, 0, stream>>>(vb, Wvb, Vt, nullptr, nullptr, 1.0f);

  attn_kernel<<<B_ * H_ * (S_ / 128), 256, 0, stream>>>(Qh, Kh, Vt, mb, ctx, att);

  gemm_bt<2><<<gg, 256, 0, stream>>>(ctx, Wob, nullptr, out, bo, 1.0f);
}

// Round 4
// 1569.624 us; speedup vs baseline: 1.0022x; 1.0022x over previous
//
#include <hip/hip_runtime.h>
#include <math.h>
#include <stdint.h>

#define B_   4
#define S_   2048
#define DM_  1024
#define H_   16
#define DK_  64

typedef __bf16 bhalf;
typedef __bf16 bhalf8 __attribute__((ext_vector_type(8)));
typedef float  f32x4  __attribute__((ext_vector_type(4)));

typedef const __attribute__((address_space(1))) void g_void;
typedef __attribute__((address_space(3))) void l_void;

// async global->LDS, 16B per lane. LDS dest must be wave-uniform base + lane*16.
__device__ __forceinline__ void gld16(const void* g, void* l) {
  __builtin_amdgcn_global_load_lds((g_void*)g, (l_void*)l, 16, 0, 0);
}

// ---------------- fp32 -> bf16 convert, merged launches ----------------
__device__ __forceinline__ void cvt_body(const float* __restrict__ s, bhalf* __restrict__ d) {
  int i = (blockIdx.x * 256 + threadIdx.x) * 8;
  float4 a = *(const float4*)(s + i);
  float4 b = *(const float4*)(s + i + 4);
  bhalf8 o;
  o[0] = (bhalf)a.x; o[1] = (bhalf)a.y; o[2] = (bhalf)a.z; o[3] = (bhalf)a.w;
  o[4] = (bhalf)b.x; o[5] = (bhalf)b.y; o[6] = (bhalf)b.z; o[7] = (bhalf)b.w;
  *(bhalf8*)(d + i) = o;
}

__global__ __launch_bounds__(256) void cvt3_kernel(const float* __restrict__ s0, const float* __restrict__ s1,
                                                   const float* __restrict__ s2, bhalf* __restrict__ d0,
                                                   bhalf* __restrict__ d1, bhalf* __restrict__ d2) {
  const float* s = blockIdx.y == 0 ? s0 : blockIdx.y == 1 ? s1 : s2;
  bhalf* d = blockIdx.y == 0 ? d0 : blockIdx.y == 1 ? d1 : d2;
  cvt_body(s, d);
}

__global__ __launch_bounds__(256) void cvt4_kernel(const float* __restrict__ s0, const float* __restrict__ s1,
                                                   const float* __restrict__ s2, const float* __restrict__ s3,
                                                   bhalf* __restrict__ d0, bhalf* __restrict__ d1,
                                                   bhalf* __restrict__ d2, bhalf* __restrict__ d3) {
  const float* s = blockIdx.y == 0 ? s0 : blockIdx.y == 1 ? s1 : blockIdx.y == 2 ? s2 : s3;
  bhalf* d = blockIdx.y == 0 ? d0 : blockIdx.y == 1 ? d1 : blockIdx.y == 2 ? d2 : d3;
  cvt_body(s, d);
}

// ---------------- mask int32 -> bit-packed u64 words ----------------
__global__ __launch_bounds__(256) void maskpack_kernel(const int* __restrict__ mask,
                                                       unsigned long long* __restrict__ out) {
  int i = blockIdx.x * 256 + threadIdx.x;   // over B*S*S
  unsigned long long bits = __ballot(mask[i] != 0);
  if ((threadIdx.x & 63) == 0) out[i >> 6] = bits;
}

// ---------------- bf16 GEMM  C[M=8192, N=1024] = A * B^T  (K=1024) ----------------
template <int MODE>
__global__ __launch_bounds__(256) void gemm_bt(const bhalf* __restrict__ A,
                                               const bhalf* __restrict__ Bm,
                                               bhalf* __restrict__ d16,
                                               float* __restrict__ d32,
                                               const float* __restrict__ bias,
                                               float scale) {
  constexpr int K = 1024;
  __shared__ __align__(16) bhalf As[128 * 64];
  __shared__ __align__(16) bhalf Bs[128 * 64];
  const int tid = threadIdx.x;
  const int lane = tid & 63;
  const int w = tid >> 6;
  const int wm = w & 1, wn = w >> 1;
  // XCD-aware swizzle: flat grid is (8, 64) = 512 WGs, 512 % 8 == 0.
  // XCD x gets wg ids [64x, 64x+64) -> contiguous bm panel (A reuse in its L2).
  const int flat = blockIdx.y * gridDim.x + blockIdx.x;
  const int nwg = gridDim.x * gridDim.y;
  const int wg = (flat & 7) * (nwg >> 3) + (flat >> 3);
  const int bm = wg >> 3, bn = wg & 7;
  const bhalf* Ab = A + (long)bm * 128 * K;
  const bhalf* Bb = Bm + (long)bn * 128 * K;
  const int l15 = lane & 15, l4 = lane >> 4;
  f32x4 acc[4][4] = {};
  for (int kt = 0; kt < K / 64; ++kt) {
#pragma unroll
    for (int j = 0; j < 4; ++j) {
      int c = j * 256 + tid;                 // 1024 chunks of 16B per tile
      int r = c >> 3, ko = (c & 7) * 8;
      gld16(Ab + (long)r * K + kt * 64 + ko, &As[c * 8]);
      gld16(Bb + (long)r * K + kt * 64 + ko, &Bs[c * 8]);
    }
    __syncthreads();
#pragma unroll
    for (int t = 0; t < 2; ++t) {
      bhalf8 af[4], bfr[4];
#pragma unroll
      for (int i = 0; i < 4; ++i)
        af[i] = *(const bhalf8*)&As[(wm * 64 + i * 16 + l15) * 64 + t * 32 + l4 * 8];
#pragma unroll
      for (int j = 0; j < 4; ++j)
        bfr[j] = *(const bhalf8*)&Bs[(wn * 64 + j * 16 + l15) * 64 + t * 32 + l4 * 8];
#pragma unroll
      for (int i = 0; i < 4; ++i)
#pragma unroll
        for (int j = 0; j < 4; ++j)
          acc[i][j] = __builtin_amdgcn_mfma_f32_16x16x32_bf16(af[i], bfr[j], acc[i][j], 0, 0, 0);
    }
    __syncthreads();
  }
#pragma unroll
  for (int i = 0; i < 4; ++i) {
#pragma unroll
    for (int j = 0; j < 4; ++j) {
#pragma unroll
      for (int r = 0; r < 4; ++r) {
        int gm = bm * 128 + wm * 64 + i * 16 + l4 * 4 + r;
        int gn = bn * 128 + wn * 64 + j * 16 + l15;
        float v = acc[i][j][r];
        if (MODE == 0) {
          int b = gm >> 11, s = gm & 2047, h = gn >> 6, d = gn & 63;
          d16[((long)(b * H_ + h) * S_ + s) * DK_ + d] = (bhalf)(v * scale);
        } else if (MODE == 1) {
          int b = gm >> 11, s = gm & 2047, h = gn >> 6, d = gn & 63;
          d16[((long)(b * H_ + h) * DK_ + d) * S_ + s] = (bhalf)v;
        } else {
          d32[(long)gm * 1024 + gn] = v + bias[gn];
        }
      }
    }
  }
}

// ---------------- staging helpers for attn (pre-swizzled global source, linear LDS dest) ----
// K tile: 128 rows x 64 bf16 (128 B rows), swizzle byte ^= (row&7)<<4
__device__ __forceinline__ void stage_k(const char* Kg, bhalf* dst, int tid) {
#pragma unroll
  for (int j = 0; j < 4; ++j) {
    int c = j * 256 + tid, r = c >> 3, ko = (c & 7) * 16;
    gld16(Kg + r * 128 + (ko ^ ((r & 7) << 4)), (char*)dst + c * 16);
  }
}
// V tile: 64 rows (d) x 128 bf16 (256 B rows) gathered from Vt[d][S], swizzle byte ^= (d&15)<<4
__device__ __forceinline__ void stage_v(const char* Vg, bhalf* dst, int tid) {
#pragma unroll
  for (int j = 0; j < 4; ++j) {
    int c = j * 256 + tid, d = c >> 4, so = (c & 15) * 16;
    gld16(Vg + (long)d * (S_ * 2) + (so ^ ((d & 15) << 4)), (char*)dst + c * 16);
  }
}

// ---------------- fused attention: scores+mask+softmax+P-write+PV ----------------
// grid: B*H*16 workgroups; each handles (b,h, 128-row q tile), two passes over K.
// vmcnt discipline: vmcnt counts loads AND stores in one in-order FIFO. Every wait
// below counts only ops PROVABLY issued after the op being waited on (asm memory
// clobbers delimit regions; global_load_lds intrinsics keep mutual order). The att
// stores and mask prefetch loads are left in flight across iterations — never drained
// at the top-of-iteration wait.
__global__ __launch_bounds__(256, 2) void attn_kernel(const bhalf* __restrict__ Qh,
                                                      const bhalf* __restrict__ Kh,
                                                      const bhalf* __restrict__ Vt,
                                                      const unsigned long long* __restrict__ mb,
                                                      bhalf* __restrict__ ctx,
                                                      float* __restrict__ att) {
  // exactly 80 KB LDS -> 2 blocks/CU
  __shared__ __align__(16) bhalf Kbuf[2][128 * 64];  // 32 KB, swizzled ^(r&7)<<4
  __shared__ __align__(16) bhalf Vs[64 * 128];       // 16 KB, swizzled ^(d&15)<<4; aliases rsum in pass 1
  __shared__ __align__(16) bhalf Ps[128 * 128];      // 32 KB, swizzled ^(q&15)<<4; Q staging at prologue
  float* rsum = (float*)Vs;

  const int tid = threadIdx.x, lane = tid & 63, w = tid >> 6;
  const int wm = w & 1, wn = w >> 1;
  const int l15 = lane & 15, l4 = lane >> 4;
  const int bid = blockIdx.x;
  const int qt = bid & 15;
  const int bh = bid >> 4;        // b*16 + h
  const int b = bh >> 4;
  const long qkBase = (long)bh * S_ * DK_;
  const bhalf* Kbase = Kh + qkBase;
  const char*  Vbase = (const char*)(Vt + qkBase);
  const int lrow0 = wm * 64 + l4 * 4;
  const long mrowbase = ((long)b * S_ + qt * 128 + lrow0) * 32 + wn;

  if (tid < 128) rsum[tid] = 0.f;

  // ---- prologue: stage Q (linear) into Ps, K(0) into Kbuf[0] ----
  {
    const bhalf* Qg = Qh + qkBase + (long)qt * 128 * DK_;
#pragma unroll
    for (int j = 0; j < 4; ++j) { int c = j * 256 + tid; gld16(Qg + c * 8, (char*)Ps + c * 16); }
  }
  stage_k((const char*)Kbase, Kbuf[0], tid);
  asm volatile("s_waitcnt vmcnt(4) lgkmcnt(0)" ::: "memory");  // Q landed (K0 stays in flight)
  __builtin_amdgcn_s_barrier();

  // hoist Q fragments into registers (loop-invariant for both passes)
  bhalf8 qf[4][2];
#pragma unroll
  for (int i = 0; i < 4; ++i)
#pragma unroll
    for (int t = 0; t < 2; ++t)
      qf[i][t] = *(const bhalf8*)((const char*)Ps + (wm * 64 + i * 16 + l15) * 128 + t * 64 + l4 * 16);

  unsigned long long mw[4][4];
#pragma unroll
  for (int i = 0; i < 4; ++i)
#pragma unroll
    for (int r = 0; r < 4; ++r) mw[i][r] = mb[mrowbase + (i * 16 + r) * 32];
  asm volatile("s_waitcnt vmcnt(20)" ::: "memory");   // no-op count; pins mw0 above loop

  // -------- pass 1: row sums of exp2(s) --------
  float psum[4][4] = {};
#pragma unroll 1
  for (int kt = 0; kt < 16; ++kt) {
    if (kt < 15) {
      stage_k((const char*)(Kbase + (kt + 1) * 128 * DK_), Kbuf[(kt + 1) & 1], tid);
      // need K(kt): certainly-after = mw(kt) 16 + K(kt+1) 4 = 20
      asm volatile("s_waitcnt vmcnt(20)" ::: "memory");
    } else {
      asm volatile("s_waitcnt vmcnt(16)" ::: "memory");
    }
    __builtin_amdgcn_s_barrier();
    const bhalf* Kc = Kbuf[kt & 1];
#pragma unroll
    for (int i = 0; i < 4; ++i) {
      unsigned int mlo[4], mhi[4];
#pragma unroll
      for (int r = 0; r < 4; ++r) {
        unsigned long long sh = mw[i][r] >> l15;
        mlo[r] = (unsigned int)sh; mhi[r] = (unsigned int)(sh >> 32);
      }
#pragma unroll
      for (int jn = 0; jn < 4; ++jn) {
        const int kr = wn * 64 + jn * 16 + l15;
        bhalf8 bk0 = *(const bhalf8*)((const char*)Kc + ((kr * 128 + l4 * 16) ^ ((kr & 7) << 4)));
        bhalf8 bk1 = *(const bhalf8*)((const char*)Kc + ((kr * 128 + 64 + l4 * 16) ^ ((kr & 7) << 4)));
        f32x4 sacc = {};
        sacc = __builtin_amdgcn_mfma_f32_16x16x32_bf16(qf[i][0], bk0, sacc, 0, 0, 0);
        sacc = __builtin_amdgcn_mfma_f32_16x16x32_bf16(qf[i][1], bk1, sacc, 0, 0, 0);
#pragma unroll
        for (int r = 0; r < 4; ++r) {
          unsigned int on = (jn < 2 ? mlo[r] : mhi[r]) & (1u << ((jn & 1) * 16));
          psum[i][r] += on ? __builtin_amdgcn_exp2f(sacc[r]) : 0.f;
        }
      }
    }
    if (kt < 15) {   // prefetch next mask words under this tile's compute
#pragma unroll
      for (int i = 0; i < 4; ++i)
#pragma unroll
        for (int r = 0; r < 4; ++r) mw[i][r] = mb[mrowbase + (i * 16 + r) * 32 + (kt + 1) * 2];
      asm volatile("s_waitcnt vmcnt(20)" ::: "memory");  // no-op count; pins mw above next stage_k
    }
    __builtin_amdgcn_s_barrier();
  }

  // reduce across the 16 lanes holding one row's columns -> rsum, then l2r = -log2(rsum)
#pragma unroll
  for (int i = 0; i < 4; ++i)
#pragma unroll
    for (int r = 0; r < 4; ++r) {
      float v = psum[i][r];
      v += __shfl_xor(v, 1); v += __shfl_xor(v, 2);
      v += __shfl_xor(v, 4); v += __shfl_xor(v, 8);
      if (l15 == 0) atomicAdd(&rsum[lrow0 + i * 16 + r], v);
    }
  __syncthreads();
  if (tid < 128) rsum[tid] = -__log2f(rsum[tid]);
  __syncthreads();
  float l2r[4][4];
#pragma unroll
  for (int i = 0; i < 4; ++i)
#pragma unroll
    for (int r = 0; r < 4; ++r) l2r[i][r] = rsum[lrow0 + i * 16 + r];
  __syncthreads();   // rsum reads done before V(0) staging overwrites Vs

  // -------- pass 2 prologue: K(0), M(0), V(0) in flight --------
  stage_k((const char*)Kbase, Kbuf[0], tid);
#pragma unroll
  for (int i = 0; i < 4; ++i)
#pragma unroll
    for (int r = 0; r < 4; ++r) mw[i][r] = mb[mrowbase + (i * 16 + r) * 32];
  asm volatile("s_waitcnt vmcnt(20)" ::: "memory");   // no-op count; region fence
  stage_v(Vbase, Vs, tid);

  f32x4 oacc[2][4] = {};
  const int prow = w * 32;   // PV: wave w handles q rows [prow, prow+32)
#pragma unroll 1
  for (int kt = 0; kt < 16; ++kt) {
    const int cur = kt & 1;
    if (kt == 0) {
      stage_k((const char*)(Kbase + 128 * DK_), Kbuf[1], tid);
      // need K0: certainly-after = V0 4 + K1 4 = 8
      asm volatile("s_waitcnt vmcnt(8)" ::: "memory");
    } else if (kt < 15) {
      stage_k((const char*)(Kbase + (kt + 1) * 128 * DK_), Kbuf[cur ^ 1], tid);
      // need K(kt): certainly-after = mw 16 + stores 16 + V 4 + K(kt+1) 4 = 40
      asm volatile("s_waitcnt vmcnt(40)" ::: "memory");
    } else {
      asm volatile("s_waitcnt vmcnt(36)" ::: "memory");
    }
    __builtin_amdgcn_s_barrier();
    const bhalf* Kc = Kbuf[cur];
    // QK^T + mask + exp2 (with -log2(rowsum) as C-init) + immediate P write
#pragma unroll
    for (int i = 0; i < 4; ++i) {
      f32x4 cin;
      unsigned int mlo[4], mhi[4];
#pragma unroll
      for (int r = 0; r < 4; ++r) {
        cin[r] = l2r[i][r];
        unsigned long long sh = mw[i][r] >> l15;
        mlo[r] = (unsigned int)sh; mhi[r] = (unsigned int)(sh >> 32);
      }
#pragma unroll
      for (int jn = 0; jn < 4; ++jn) {
        const int kr = wn * 64 + jn * 16 + l15;
        bhalf8 bk0 = *(const bhalf8*)((const char*)Kc + ((kr * 128 + l4 * 16) ^ ((kr & 7) << 4)));
        bhalf8 bk1 = *(const bhalf8*)((const char*)Kc + ((kr * 128 + 64 + l4 * 16) ^ ((kr & 7) << 4)));
        f32x4 sacc = cin;
        sacc = __builtin_amdgcn_mfma_f32_16x16x32_bf16(qf[i][0], bk0, sacc, 0, 0, 0);
        sacc = __builtin_amdgcn_mfma_f32_16x16x32_bf16(qf[i][1], bk1, sacc, 0, 0, 0);
        const int pc2 = (wn * 64 + jn * 16 + l15) * 2;
#pragma unroll
        for (int r = 0; r < 4; ++r) {
          unsigned int on = (jn < 2 ? mlo[r] : mhi[r]) & (1u << ((jn & 1) * 16));
          float p = on ? __builtin_amdgcn_exp2f(sacc[r]) : 0.f;
          const int pr = lrow0 + i * 16 + r;
          *(bhalf*)((char*)Ps + pr * 256 + (pc2 ^ ((pr & 15) << 4))) = (bhalf)p;
        }
      }
    }
    // P writes visible + V(kt) landed. Stores/mw from kt-1 are a full iteration old.
    if (kt < 15) asm volatile("s_waitcnt vmcnt(4) lgkmcnt(0)" ::: "memory");
    else         asm volatile("s_waitcnt vmcnt(0) lgkmcnt(0)" ::: "memory");
    __builtin_amdgcn_s_barrier();
    if (kt < 15) {
      // mask prefetch BEFORE the att stores, so neither the compiler's mask-use wait
      // nor the top wait ever forces the store stream to drain.
#pragma unroll
      for (int i = 0; i < 4; ++i)
#pragma unroll
        for (int r = 0; r < 4; ++r) mw[i][r] = mb[mrowbase + (i * 16 + r) * 32 + (kt + 1) * 2];
      asm volatile("s_waitcnt vmcnt(20)" ::: "memory");   // no-op count; pins mw above stores
    }
    // coalesced normalized-attention write (fp32, nontemporal, never waited on here)
    {
      float* dst = att + ((long)bh * S_ + qt * 128) * S_ + kt * 128;
#pragma unroll
      for (int rep = 0; rep < 8; ++rep) {
        int idx = rep * 256 + tid;      // 2048 groups of 8 bf16
        int row = idx >> 4, slot = idx & 15;
        bhalf8 p8 = *(const bhalf8*)((const char*)Ps + row * 256 + ((slot * 16) ^ ((row & 15) << 4)));
        f32x4 o0, o1;
        o0[0] = (float)p8[0]; o0[1] = (float)p8[1]; o0[2] = (float)p8[2]; o0[3] = (float)p8[3];
        o1[0] = (float)p8[4]; o1[1] = (float)p8[5]; o1[2] = (float)p8[6]; o1[3] = (float)p8[7];
        float* dp = dst + (long)row * S_ + slot * 8;
        __builtin_nontemporal_store(o0, (f32x4*)dp);
        __builtin_nontemporal_store(o1, (f32x4*)(dp + 4));
      }
    }
    // PV: oacc += P(128x128) * V(128x64)
    __builtin_amdgcn_s_setprio(1);
#pragma unroll
    for (int t = 0; t < 4; ++t) {
      bhalf8 ap[2], bv[4];
#pragma unroll
      for (int mi = 0; mi < 2; ++mi) {
        const int pr = prow + mi * 16 + l15;
        ap[mi] = *(const bhalf8*)((const char*)Ps + pr * 256 + ((t * 64 + l4 * 16) ^ ((pr & 15) << 4)));
      }
#pragma unroll
      for (int nj = 0; nj < 4; ++nj) {
        const int vr = nj * 16 + l15;
        bv[nj] = *(const bhalf8*)((const char*)Vs + vr * 256 + ((t * 64 + l4 * 16) ^ ((vr & 15) << 4)));
      }
#pragma unroll
      for (int mi = 0; mi < 2; ++mi)
#pragma unroll
        for (int nj = 0; nj < 4; ++nj)
          oacc[mi][nj] = __builtin_amdgcn_mfma_f32_16x16x32_bf16(ap[mi], bv[nj], oacc[mi][nj], 0, 0, 0);
    }
    __builtin_amdgcn_s_setprio(0);
    __builtin_amdgcn_s_barrier();   // all Ps/Vs reads done before restage
    if (kt < 15) {
      stage_v(Vbase + (kt + 1) * 256, Vs, tid);
      asm volatile("s_waitcnt vmcnt(40)" ::: "memory");   // no-op count; end-of-iter region fence
    }
  }
  // write context (bf16) into [B*S, DM] assembly buffer
#pragma unroll
  for (int mi = 0; mi < 2; ++mi)
#pragma unroll
    for (int nj = 0; nj < 4; ++nj)
#pragma unroll
      for (int r = 0; r < 4; ++r) {
        int lq = prow + mi * 16 + l4 * 4 + r;
        int d = nj * 16 + l15;
        int gq = qt * 128 + lq;
        ctx[((long)(b * S_ + gq)) * DM_ + (bh & 15) * DK_ + d] = (bhalf)oacc[mi][nj][r];
      }
}

extern "C" void kernel_launch(void* const* d_in, const int* in_sizes, int n_in,
                              void* d_out, int out_size, void* d_ws, size_t ws_size,
                              hipStream_t stream) {
  const float* q  = (const float*)d_in[0];
  const float* k  = (const float*)d_in[1];
  const float* v  = (const float*)d_in[2];
  const int*   mask = (const int*)d_in[3];
  const float* Wq = (const float*)d_in[4];
  const float* Wk = (const float*)d_in[5];
  const float* Wv = (const float*)d_in[6];
  const float* Wo = (const float*)d_in[7];
  const float* bo = (const float*)d_in[8];
  float* out = (float*)d_out;
  float* att = out + (size_t)B_ * S_ * DM_;

  char* ws = (char*)d_ws;
  bhalf* qb  = (bhalf*)(ws);
  bhalf* kb  = (bhalf*)(ws + (16ull << 20));
  bhalf* vb  = (bhalf*)(ws + (32ull << 20));
  bhalf* Wqb = (bhalf*)(ws + (48ull << 20));
  bhalf* Wkb = (bhalf*)(ws + (50ull << 20));
  bhalf* Wvb = (bhalf*)(ws + (52ull << 20));
  bhalf* Wob = (bhalf*)(ws + (54ull << 20));
  bhalf* Qh  = (bhalf*)(ws + (56ull << 20));
  bhalf* Kh  = (bhalf*)(ws + (72ull << 20));
  bhalf* Vt  = (bhalf*)(ws + (88ull << 20));
  bhalf* ctx = (bhalf*)(ws + (104ull << 20));
  unsigned long long* mb = (unsigned long long*)(ws + (120ull << 20));

  const int NQKV = B_ * S_ * DM_;    // 8388608
  const int NW = DM_ * DM_;          // 1048576
  dim3 g3(NQKV / 2048, 3);
  cvt3_kernel<<<g3, 256, 0, stream>>>(q, k, v, qb, kb, vb);
  dim3 g4(NW / 2048, 4);
  cvt4_kernel<<<g4, 256, 0, stream>>>(Wq, Wk, Wv, Wo, Wqb, Wkb, Wvb, Wob);
  maskpack_kernel<<<(B_ * S_ * S_) / 256, 256, 0, stream>>>(mask, mb);

  dim3 gg(DM_ / 128, (B_ * S_) / 128);   // (8, 64)
  // Qh scale = (1/sqrt(dk)) * log2(e) so scores are in the exp2 domain
  gemm_bt<0><<<gg, 256, 0, stream>>>(qb, Wqb, Qh, nullptr, nullptr, 0.18033688011112042f);
  gemm_bt<0><<<gg, 256, 0, stream>>>(kb, Wkb, Kh, nullptr, nullptr, 1.0f);
  gemm_bt<1><<<gg, 256, 0, stream>>>(vb, Wvb, Vt, nullptr, nullptr, 1.0f);

  attn_kernel<<<B_ * H_ * (S_ / 128), 256, 0, stream>>>(Qh, Kh, Vt, mb, ctx, att);

  gemm_bt<2><<<gg, 256, 0, stream>>>(ctx, Wob, nullptr, out, bo, 1.0f);
}